// Round 11
// baseline (43.321 us; speedup 1.0000x reference)
//
#include <hip/hip_runtime.h>
#include <string.h>

// VectorQuantizer: N=65536 rows, K=1024 codes, D=16, fp32.
// Out layout (fp32): z_q_st [0,1048576) | loss [1048576] | indices-as-float [1048577,1114113)
// R11: R10's proven numerics; occupancy max-out:
//   - K split in QUARTERS (8 tiles/wave), 1 row-tile per 4-wave block
//   - 2048 blocks = 8 blocks/CU = 8 waves/SIMD (hw max), __launch_bounds__(256,8)
//   - e2+0.5 hoisted to 8 regs/wave (both passes)

typedef __bf16 bf16x8 __attribute__((ext_vector_type(8)));
typedef float  f32x16 __attribute__((ext_vector_type(16)));

constexpr int BLOCK = 256;
constexpr int NROWS = 65536;
constexpr int K = 1024;
constexpr int RPB = 32;               // one 32-row MFMA tile per block
constexpr int NBLK = NROWS / RPB;     // 2048 blocks = 8/CU
constexpr int TPW = 8;                // k-tiles per wave (quarter of 32)
constexpr int CAP = 96;               // per-wave candidate capacity (E[cnt]~8)
constexpr float BAND = 1.5e-3f;       // proven R6/R8/R10 (absmax 0)
constexpr int OFF_LOSS = 1048576;
constexpr int OFF_IDX  = 1048577;

// numpy pairwise_sum (n=16) of squares — bitwise matches np.sum(x**2, axis=1).
__device__ __forceinline__ float np_sumsq16(const float* a) {
  float s[16];
#pragma unroll
  for (int j = 0; j < 16; ++j) s[j] = __fmul_rn(a[j], a[j]);
  float r[8];
#pragma unroll
  for (int j = 0; j < 8; ++j) r[j] = __fadd_rn(s[j], s[j + 8]);
  const float t0 = __fadd_rn(r[0], r[1]);
  const float t1 = __fadd_rn(r[2], r[3]);
  const float t2 = __fadd_rn(r[4], r[5]);
  const float t3 = __fadd_rn(r[6], r[7]);
  return __fadd_rn(__fadd_rn(t0, t1), __fadd_rn(t2, t3));
}

// exact distance, identical rounding structure to R1..R10 (absmax 0 on this dataset)
__device__ __forceinline__ float np_dist(const float* zz, const float* ee,
                                         float z2, float e2k) {
  float c0 = zz[0]*ee[0];   c0 = fmaf(zz[1],ee[1],c0);   c0 = fmaf(zz[2],ee[2],c0);   c0 = fmaf(zz[3],ee[3],c0);
  float c1 = zz[4]*ee[4];   c1 = fmaf(zz[5],ee[5],c1);   c1 = fmaf(zz[6],ee[6],c1);   c1 = fmaf(zz[7],ee[7],c1);
  float c2 = zz[8]*ee[8];   c2 = fmaf(zz[9],ee[9],c2);   c2 = fmaf(zz[10],ee[10],c2); c2 = fmaf(zz[11],ee[11],c2);
  float c3 = zz[12]*ee[12]; c3 = fmaf(zz[13],ee[13],c3); c3 = fmaf(zz[14],ee[14],c3); c3 = fmaf(zz[15],ee[15],c3);
  const float dot = __fadd_rn(__fadd_rn(c0, c1), __fadd_rn(c2, c3));
  return __fmaf_rn(-2.0f, dot, __fadd_rn(z2, e2k));
}

// vq_pre: pack bf16 B-frags (tile tt, col c -> tt*1024 + c*16 (+512 hi)) + e2
__global__ __launch_bounds__(256)
void vq_pre(const float* __restrict__ emb, float* __restrict__ e2g,
            char* __restrict__ Bpack) {
  const int r = blockIdx.x * 256 + threadIdx.x;   // 4 blocks x 256 = 1024 codes
  const float4* g4 = reinterpret_cast<const float4*>(emb);
  float ee[16];
  float4* ev = reinterpret_cast<float4*>(ee);
#pragma unroll
  for (int j = 0; j < 4; ++j) ev[j] = g4[r * 4 + j];
  e2g[r] = np_sumsq16(ee);
  unsigned int wd[8];
#pragma unroll
  for (int j = 0; j < 8; ++j) {
    __bf16 lo = (__bf16)ee[2*j], hi = (__bf16)ee[2*j+1];   // RNE hw cvt
    unsigned short ulo, uhi;
    memcpy(&ulo, &lo, 2); memcpy(&uhi, &hi, 2);
    wd[j] = (unsigned int)ulo | ((unsigned int)uhi << 16);
  }
  const int tt = r >> 5, c = r & 31;
  *reinterpret_cast<uint4*>(Bpack + tt*1024 + c*16)       = make_uint4(wd[0], wd[1], wd[2], wd[3]);
  *reinterpret_cast<uint4*>(Bpack + tt*1024 + 512 + c*16) = make_uint4(wd[4], wd[5], wd[6], wd[7]);
}

__global__ __launch_bounds__(BLOCK, 8)   // 8 waves/SIMD target: VGPR capped at 64
void vq_main(const float* __restrict__ z, const float* __restrict__ emb,
             const float* __restrict__ e2g, const char* __restrict__ Bpack,
             float* __restrict__ out, float* __restrict__ partials) {
  __shared__ unsigned int sclist[4][CAP];          // 1.5 KB candidates (row<<16|k)
  __shared__ unsigned long long smin64[RPB];       // 256 B winner keys (block-shared)
  __shared__ float smin[4][RPB];                   // pass-A row mins per wave
  __shared__ int   scnt[4];

  const int t = threadIdx.x;
  const int lane = t & 63;
  const int w = t >> 6;             // k-quarter id; all waves share the row-tile
  const int h = lane >> 5;
  const int rr = lane & 31;

  const float4* g4 = reinterpret_cast<const float4*>(emb);
  const float4* z4 = reinterpret_cast<const float4*>(z);

  if (lane == 0) scnt[w] = 0;
  if (t < RPB) smin64[t] = ~0ull;

  // ---- A-frag: the block's 32 z rows -> bf16 (lane: row rr, K-elems 8h..8h+7) ----
  const int wrow0 = blockIdx.x * RPB;
  const float* zrow = z + (size_t)(wrow0 + rr) * 16 + h * 8;
  const float4 a0 = *reinterpret_cast<const float4*>(zrow);
  const float4 a1 = *reinterpret_cast<const float4*>(zrow + 4);
  bf16x8 af;
  af[0]=(__bf16)a0.x; af[1]=(__bf16)a0.y; af[2]=(__bf16)a0.z; af[3]=(__bf16)a0.w;
  af[4]=(__bf16)a1.x; af[5]=(__bf16)a1.y; af[6]=(__bf16)a1.z; af[7]=(__bf16)a1.w;

  const int kt0 = w * TPW;            // my k-quarter: tiles [kt0, kt0+TPW)
  const bf16x8* bfp = reinterpret_cast<const bf16x8*>(Bpack + (size_t)lane * 16);

  // ---- hoist pre = e2 + 0.5 for my 8 tiles (reused by both passes) ----
  float e2r[TPW];
#pragma unroll
  for (int j = 0; j < TPW; ++j) e2r[j] = e2g[(kt0 + j) * 32 + rr] + 0.5f;

  // ---- pass A: per-row approx min over my k-quarter ----
  float runm[16];
#pragma unroll
  for (int i = 0; i < 16; ++i) runm[i] = __builtin_inff();

#pragma unroll 4
  for (int tt = kt0; tt < kt0 + TPW; ++tt) {
    f32x16 zc = {};
    f32x16 acc = __builtin_amdgcn_mfma_f32_32x32x16_bf16(af, bfp[tt * 64], zc, 0, 0, 0);
    const float pre = e2r[tt - kt0];
#pragma unroll
    for (int i = 0; i < 16; ++i)
      runm[i] = fminf(runm[i], __fmaf_rn(-2.0f, acc[i], pre));
  }

  // cross-lane min over 32 cols (halves hold disjoint rows)
#pragma unroll
  for (int i = 0; i < 16; ++i)
#pragma unroll
    for (int m = 1; m < 32; m <<= 1)
      runm[i] = fminf(runm[i], __shfl_xor(runm[i], m));

  // ---- merge mins across the 4 k-quarters (physical-row indexed, order-indep) ----
  if (rr == 0) {
#pragma unroll
    for (int i = 0; i < 16; ++i)
      smin[w][(i & 3) + 8 * (i >> 2) + 4 * h] = runm[i];
  }
  __syncthreads();
#pragma unroll
  for (int i = 0; i < 16; ++i) {
    const int pr = (i & 3) + 8 * (i >> 2) + 4 * h;
    runm[i] = fminf(fminf(smin[0][pr], smin[1][pr]),
                    fminf(smin[2][pr], smin[3][pr])) + BAND;
  }

  // ---- pass B: recompute (bitwise-identical), per-lane atomic collect (proven) ----
#pragma unroll 4
  for (int tt = kt0; tt < kt0 + TPW; ++tt) {
    f32x16 zc = {};
    f32x16 acc = __builtin_amdgcn_mfma_f32_32x32x16_bf16(af, bfp[tt * 64], zc, 0, 0, 0);
    const float pre = e2r[tt - kt0];
    const int kcol = tt * 32 + rr;
#pragma unroll
    for (int i = 0; i < 16; ++i) {
      const float m = __fmaf_rn(-2.0f, acc[i], pre);
      if (m <= runm[i]) {
        const int rowloc = (i & 3) + 8 * (i >> 2) + 4 * h;
        const int slot = atomicAdd(&scnt[w], 1);
        if (slot < CAP) sclist[w][slot] = ((unsigned)rowloc << 16) | (unsigned)kcol;
      }
    }
  }
  int cnt = scnt[w]; if (cnt > CAP) cnt = CAP;   // own wave's LDS ops in issue order

  // ---- exact rescore (lane-parallel) + u64 atomicMin winner (order-independent;
  //      d>0 so float-bit order == numeric; ties -> smaller k == np first-index) ----
  for (int j0 = 0; j0 < cnt; j0 += 64) {
    const int j = j0 + lane;
    if (j < cnt) {
      const unsigned ent = sclist[w][j];
      const int rowj = (int)(ent >> 16), kj = (int)(ent & 1023);
      float zz[16]; float4* zv = reinterpret_cast<float4*>(zz);
#pragma unroll
      for (int q = 0; q < 4; ++q) zv[q] = z4[(size_t)(wrow0 + rowj) * 4 + q];
      float ee[16]; float4* ev = reinterpret_cast<float4*>(ee);
#pragma unroll
      for (int q = 0; q < 4; ++q) ev[q] = g4[(size_t)kj * 4 + q];
      const float d = np_dist(zz, ee, np_sumsq16(zz), e2g[kj]);
      const unsigned long long key =
          ((unsigned long long)__float_as_uint(d) << 32) | (unsigned long long)kj;
      atomicMin(&smin64[rowj], key);
    }
  }
  __syncthreads();   // all waves' atomicMins done

  // ---- wave 0: read winner per row, epilogue + block loss partial ----
  if (t < 64) {
    float lsum = 0.0f;
    if (lane < 32) {
      const int bk = (int)(smin64[lane] & 1023ull);
      const int r = wrow0 + lane;
      float zz[16]; float4* zv = reinterpret_cast<float4*>(zz);
#pragma unroll
      for (int q = 0; q < 4; ++q) zv[q] = z4[(size_t)r * 4 + q];
      float ee[16]; float4* ev = reinterpret_cast<float4*>(ee);
#pragma unroll
      for (int q = 0; q < 4; ++q) ev[q] = g4[(size_t)bk * 4 + q];
      float ov[16];
#pragma unroll
      for (int j2 = 0; j2 < 16; ++j2) {
        const float d = __fsub_rn(ee[j2], zz[j2]);   // z_q - z
        lsum = fmaf(d, d, lsum);                     // loss partial
        ov[j2] = __fadd_rn(zz[j2], d);               // z + (z_q - z) == np z_q_st rounding
      }
      float4* o4 = reinterpret_cast<float4*>(out) + (size_t)r * 4;
      const float4* ovv = reinterpret_cast<const float4*>(ov);
#pragma unroll
      for (int q = 0; q < 4; ++q) o4[q] = ovv[q];
      out[OFF_IDX + r] = (float)bk;
    }
#pragma unroll
    for (int off = 32; off > 0; off >>= 1) lsum += __shfl_down(lsum, off);
    if (lane == 0) partials[blockIdx.x] = lsum;
  }
}

__global__ __launch_bounds__(256)
void vq_fin(const float* __restrict__ partials, float* __restrict__ out) {
  const int t = threadIdx.x;
  float v = 0.0f;
#pragma unroll
  for (int j = 0; j < NBLK / 256; ++j)   // fixed order: deterministic
    v += partials[t + 256 * j];
#pragma unroll
  for (int off = 32; off > 0; off >>= 1) v += __shfl_down(v, off);
  __shared__ float s[4];
  if ((t & 63) == 0) s[t >> 6] = v;
  __syncthreads();
  if (t == 0) {
    const float S = (s[0] + s[1]) + (s[2] + s[3]);
    const float m = S / 1048576.0f;      // np.mean
    out[OFF_LOSS] = 1.25f * m;           // m + COMMITMENT_COST*m
  }
}

extern "C" void kernel_launch(void* const* d_in, const int* in_sizes, int n_in,
                              void* d_out, int out_size, void* d_ws, size_t ws_size,
                              hipStream_t stream) {
  const float* z   = reinterpret_cast<const float*>(d_in[0]);
  const float* emb = reinterpret_cast<const float*>(d_in[1]);
  float* out       = reinterpret_cast<float*>(d_out);
  float* e2g       = reinterpret_cast<float*>(d_ws);          // [0,1024) ||e_k||^2
  float* partials  = e2g + K;                                 // [1024,3072) 2048 partials
  char*  Bpack     = reinterpret_cast<char*>(e2g + 3072);     // 32 KB bf16 frag table
  vq_pre <<<K / 256, 256, 0, stream>>>(emb, e2g, Bpack);
  vq_main<<<NBLK, BLOCK, 0, stream>>>(z, emb, e2g, Bpack, out, partials);
  vq_fin <<<1, 256, 0, stream>>>(partials, out);
}

// Round 12
// 36.566 us; speedup vs baseline: 1.1847x; 1.1847x over previous
//
#include <hip/hip_runtime.h>
#include <string.h>

// VectorQuantizer: N=65536 rows, K=1024 codes, D=16, fp32.
// Out layout (fp32): z_q_st [0,1048576) | loss [1048576] | indices-as-float [1048577,1114113)
// R12: R10's proven numerics & per-wave structure, half the blocks:
//   BLOCK=512 (8 waves = 4 independent pair-units), NBLK=512 (2 blocks/CU, 4 waves/SIMD).
//   Each pair: one 32-row MFMA tile, K split in halves across the two waves.

typedef __bf16 bf16x8 __attribute__((ext_vector_type(8)));
typedef float  f32x16 __attribute__((ext_vector_type(16)));

constexpr int BLOCK = 512;
constexpr int NROWS = 65536;
constexpr int K = 1024;
constexpr int RPB = 128;              // 4 row-tiles of 32 per block
constexpr int NBLK = NROWS / RPB;     // 512 blocks = 2/CU
constexpr int TPW = 16;               // k-tiles per wave (half of 32)
constexpr int CAP = 192;              // per-wave candidate capacity (E[cnt]~29)
constexpr float BAND = 1.5e-3f;       // proven R6/R8/R10 (absmax 0)
constexpr int OFF_LOSS = 1048576;
constexpr int OFF_IDX  = 1048577;

// numpy pairwise_sum (n=16) of squares — bitwise matches np.sum(x**2, axis=1).
__device__ __forceinline__ float np_sumsq16(const float* a) {
  float s[16];
#pragma unroll
  for (int j = 0; j < 16; ++j) s[j] = __fmul_rn(a[j], a[j]);
  float r[8];
#pragma unroll
  for (int j = 0; j < 8; ++j) r[j] = __fadd_rn(s[j], s[j + 8]);
  const float t0 = __fadd_rn(r[0], r[1]);
  const float t1 = __fadd_rn(r[2], r[3]);
  const float t2 = __fadd_rn(r[4], r[5]);
  const float t3 = __fadd_rn(r[6], r[7]);
  return __fadd_rn(__fadd_rn(t0, t1), __fadd_rn(t2, t3));
}

// exact distance, identical rounding structure to R1..R10 (absmax 0 on this dataset)
__device__ __forceinline__ float np_dist(const float* zz, const float* ee,
                                         float z2, float e2k) {
  float c0 = zz[0]*ee[0];   c0 = fmaf(zz[1],ee[1],c0);   c0 = fmaf(zz[2],ee[2],c0);   c0 = fmaf(zz[3],ee[3],c0);
  float c1 = zz[4]*ee[4];   c1 = fmaf(zz[5],ee[5],c1);   c1 = fmaf(zz[6],ee[6],c1);   c1 = fmaf(zz[7],ee[7],c1);
  float c2 = zz[8]*ee[8];   c2 = fmaf(zz[9],ee[9],c2);   c2 = fmaf(zz[10],ee[10],c2); c2 = fmaf(zz[11],ee[11],c2);
  float c3 = zz[12]*ee[12]; c3 = fmaf(zz[13],ee[13],c3); c3 = fmaf(zz[14],ee[14],c3); c3 = fmaf(zz[15],ee[15],c3);
  const float dot = __fadd_rn(__fadd_rn(c0, c1), __fadd_rn(c2, c3));
  return __fmaf_rn(-2.0f, dot, __fadd_rn(z2, e2k));
}

// vq_pre: pack bf16 B-frags (tile tt, col c -> tt*1024 + c*16 (+512 hi)) + e2
__global__ __launch_bounds__(256)
void vq_pre(const float* __restrict__ emb, float* __restrict__ e2g,
            char* __restrict__ Bpack) {
  const int r = blockIdx.x * 256 + threadIdx.x;   // 4 blocks x 256 = 1024 codes
  const float4* g4 = reinterpret_cast<const float4*>(emb);
  float ee[16];
  float4* ev = reinterpret_cast<float4*>(ee);
#pragma unroll
  for (int j = 0; j < 4; ++j) ev[j] = g4[r * 4 + j];
  e2g[r] = np_sumsq16(ee);
  unsigned int wd[8];
#pragma unroll
  for (int j = 0; j < 8; ++j) {
    __bf16 lo = (__bf16)ee[2*j], hi = (__bf16)ee[2*j+1];   // RNE hw cvt
    unsigned short ulo, uhi;
    memcpy(&ulo, &lo, 2); memcpy(&uhi, &hi, 2);
    wd[j] = (unsigned int)ulo | ((unsigned int)uhi << 16);
  }
  const int tt = r >> 5, c = r & 31;
  *reinterpret_cast<uint4*>(Bpack + tt*1024 + c*16)       = make_uint4(wd[0], wd[1], wd[2], wd[3]);
  *reinterpret_cast<uint4*>(Bpack + tt*1024 + 512 + c*16) = make_uint4(wd[4], wd[5], wd[6], wd[7]);
}

__global__ __launch_bounds__(BLOCK, 4)   // 8 waves/block, 2 blocks/CU -> 4 waves/SIMD
void vq_main(const float* __restrict__ z, const float* __restrict__ emb,
             const float* __restrict__ e2g, const char* __restrict__ Bpack,
             float* __restrict__ out, float* __restrict__ partials) {
  __shared__ unsigned int sclist[8][CAP];          // 6 KB candidates (row<<16|k)
  __shared__ unsigned long long smin64[4][32];     // 1 KB winner keys per pair
  __shared__ float smin[8][32];                    // 1 KB pass-A row mins per wave
  __shared__ int   scnt[8];
  __shared__ float sred[8];

  const int t = threadIdx.x;
  const int lane = t & 63;
  const int w = t >> 6;             // wave 0..7: pair (w>>1) owns a 32-row tile; (w&1)=k-half
  const int pair = w >> 1;
  const int h = lane >> 5;
  const int rr = lane & 31;

  const float4* g4 = reinterpret_cast<const float4*>(emb);
  const float4* z4 = reinterpret_cast<const float4*>(z);

  if (lane == 0) scnt[w] = 0;
  if (t < 128) smin64[t >> 5][t & 31] = ~0ull;     // init all 4 pairs' winner keys

  // ---- A-frag: my pair's 32 z rows -> bf16 (lane: row rr, K-elems 8h..8h+7) ----
  const int wrow0 = blockIdx.x * RPB + pair * 32;
  const float* zrow = z + (size_t)(wrow0 + rr) * 16 + h * 8;
  const float4 a0 = *reinterpret_cast<const float4*>(zrow);
  const float4 a1 = *reinterpret_cast<const float4*>(zrow + 4);
  bf16x8 af;
  af[0]=(__bf16)a0.x; af[1]=(__bf16)a0.y; af[2]=(__bf16)a0.z; af[3]=(__bf16)a0.w;
  af[4]=(__bf16)a1.x; af[5]=(__bf16)a1.y; af[6]=(__bf16)a1.z; af[7]=(__bf16)a1.w;

  const int kt0 = (w & 1) * TPW;      // my k-half: tiles [kt0, kt0+TPW)
  const bf16x8* bfp = reinterpret_cast<const bf16x8*>(Bpack + (size_t)lane * 16);

  // ---- hoist pre = e2 + 0.5 for my 16 tiles (reused by both passes) ----
  float e2r[TPW];
#pragma unroll
  for (int j = 0; j < TPW; ++j) e2r[j] = e2g[(kt0 + j) * 32 + rr] + 0.5f;

  // ---- pass A: per-row approx min over my k-half ----
  float runm[16];
#pragma unroll
  for (int i = 0; i < 16; ++i) runm[i] = __builtin_inff();

#pragma unroll 4
  for (int tt = kt0; tt < kt0 + TPW; ++tt) {
    f32x16 zc = {};
    f32x16 acc = __builtin_amdgcn_mfma_f32_32x32x16_bf16(af, bfp[tt * 64], zc, 0, 0, 0);
    const float pre = e2r[tt - kt0];
#pragma unroll
    for (int i = 0; i < 16; ++i)
      runm[i] = fminf(runm[i], __fmaf_rn(-2.0f, acc[i], pre));
  }

  // cross-lane min over 32 cols (halves hold disjoint rows)
#pragma unroll
  for (int i = 0; i < 16; ++i)
#pragma unroll
    for (int m = 1; m < 32; m <<= 1)
      runm[i] = fminf(runm[i], __shfl_xor(runm[i], m));

  // ---- merge mins across the k-half pair (physical-row indexed) ----
  if (rr == 0) {
#pragma unroll
    for (int i = 0; i < 16; ++i)
      smin[w][(i & 3) + 8 * (i >> 2) + 4 * h] = runm[i];
  }
  __syncthreads();
#pragma unroll
  for (int i = 0; i < 16; ++i)
    runm[i] = fminf(runm[i], smin[w ^ 1][(i & 3) + 8 * (i >> 2) + 4 * h]) + BAND;

  // ---- pass B: recompute (bitwise-identical), per-lane atomic collect (proven) ----
#pragma unroll 4
  for (int tt = kt0; tt < kt0 + TPW; ++tt) {
    f32x16 zc = {};
    f32x16 acc = __builtin_amdgcn_mfma_f32_32x32x16_bf16(af, bfp[tt * 64], zc, 0, 0, 0);
    const float pre = e2r[tt - kt0];
    const int kcol = tt * 32 + rr;
#pragma unroll
    for (int i = 0; i < 16; ++i) {
      const float m = __fmaf_rn(-2.0f, acc[i], pre);
      if (m <= runm[i]) {
        const int rowloc = (i & 3) + 8 * (i >> 2) + 4 * h;
        const int slot = atomicAdd(&scnt[w], 1);
        if (slot < CAP) sclist[w][slot] = ((unsigned)rowloc << 16) | (unsigned)kcol;
      }
    }
  }
  int cnt = scnt[w]; if (cnt > CAP) cnt = CAP;   // own wave's LDS ops in issue order

  // ---- exact rescore (lane-parallel) + u64 atomicMin winner (order-independent;
  //      d>0 so float-bit order == numeric; ties -> smaller k == np first-index) ----
  for (int j0 = 0; j0 < cnt; j0 += 64) {
    const int j = j0 + lane;
    if (j < cnt) {
      const unsigned ent = sclist[w][j];
      const int rowj = (int)(ent >> 16), kj = (int)(ent & 1023);
      float zz[16]; float4* zv = reinterpret_cast<float4*>(zz);
#pragma unroll
      for (int q = 0; q < 4; ++q) zv[q] = z4[(size_t)(wrow0 + rowj) * 4 + q];
      float ee[16]; float4* ev = reinterpret_cast<float4*>(ee);
#pragma unroll
      for (int q = 0; q < 4; ++q) ev[q] = g4[(size_t)kj * 4 + q];
      const float d = np_dist(zz, ee, np_sumsq16(zz), e2g[kj]);
      const unsigned long long key =
          ((unsigned long long)__float_as_uint(d) << 32) | (unsigned long long)kj;
      atomicMin(&smin64[pair][rowj], key);
    }
  }
  __syncthreads();   // all pairs' atomicMins done

  // ---- even wave of each pair: read winner per row, epilogue + loss partial ----
  float lsum = 0.0f;
  if (!(w & 1) && lane < 32) {
    const int bk = (int)(smin64[pair][lane] & 1023ull);
    const int r = wrow0 + lane;
    float zz[16]; float4* zv = reinterpret_cast<float4*>(zz);
#pragma unroll
    for (int q = 0; q < 4; ++q) zv[q] = z4[(size_t)r * 4 + q];
    float ee[16]; float4* ev = reinterpret_cast<float4*>(ee);
#pragma unroll
    for (int q = 0; q < 4; ++q) ev[q] = g4[(size_t)bk * 4 + q];
    float ov[16];
#pragma unroll
    for (int j2 = 0; j2 < 16; ++j2) {
      const float d = __fsub_rn(ee[j2], zz[j2]);   // z_q - z
      lsum = fmaf(d, d, lsum);                     // loss partial
      ov[j2] = __fadd_rn(zz[j2], d);               // z + (z_q - z) == np z_q_st rounding
    }
    float4* o4 = reinterpret_cast<float4*>(out) + (size_t)r * 4;
    const float4* ovv = reinterpret_cast<const float4*>(ov);
#pragma unroll
    for (int q = 0; q < 4; ++q) o4[q] = ovv[q];
    out[OFF_IDX + r] = (float)bk;
  }

#pragma unroll
  for (int off = 32; off > 0; off >>= 1) lsum += __shfl_down(lsum, off);
  if (lane == 0) sred[w] = lsum;
  __syncthreads();
  if (t == 0)
    partials[blockIdx.x] = ((sred[0] + sred[1]) + (sred[2] + sred[3]))
                         + ((sred[4] + sred[5]) + (sred[6] + sred[7]));
}

__global__ __launch_bounds__(256)
void vq_fin(const float* __restrict__ partials, float* __restrict__ out) {
  const int t = threadIdx.x;
  float v = partials[t] + partials[t + 256];     // 512 partials, fixed order
#pragma unroll
  for (int off = 32; off > 0; off >>= 1) v += __shfl_down(v, off);
  __shared__ float s[4];
  if ((t & 63) == 0) s[t >> 6] = v;
  __syncthreads();
  if (t == 0) {
    const float S = (s[0] + s[1]) + (s[2] + s[3]);
    const float m = S / 1048576.0f;      // np.mean
    out[OFF_LOSS] = 1.25f * m;           // m + COMMITMENT_COST*m
  }
}

extern "C" void kernel_launch(void* const* d_in, const int* in_sizes, int n_in,
                              void* d_out, int out_size, void* d_ws, size_t ws_size,
                              hipStream_t stream) {
  const float* z   = reinterpret_cast<const float*>(d_in[0]);
  const float* emb = reinterpret_cast<const float*>(d_in[1]);
  float* out       = reinterpret_cast<float*>(d_out);
  float* e2g       = reinterpret_cast<float*>(d_ws);          // [0,1024) ||e_k||^2
  float* partials  = e2g + K;                                 // [1024,1536) 512 partials
  char*  Bpack     = reinterpret_cast<char*>(e2g + 2048);     // 32 KB bf16 frag table
  vq_pre <<<K / 256, 256, 0, stream>>>(emb, e2g, Bpack);
  vq_main<<<NBLK, BLOCK, 0, stream>>>(z, emb, e2g, Bpack, out, partials);
  vq_fin <<<1, 256, 0, stream>>>(partials, out);
}